// Round 13
// baseline (734.592 us; speedup 1.0000x reference)
//
#include <hip/hip_runtime.h>
#include <hip/hip_bf16.h>
#include <math.h>

#define B_  2
#define T_  2048
#define D_  512
#define H_  8
#define HD_ 64
#define FFN_ 2048
#define VOCAB_ 256
#define BT_ (B_*T_)
#define NC_ 32            // chunks per (b,h), chunk size 64
#define CENT_ 4160        // floats per chunk state: 64*64 S + 64 z

typedef __attribute__((ext_vector_type(8))) short short8;
typedef __attribute__((ext_vector_type(4))) float float4v;
typedef __hip_bfloat16 bf16;

// async 16B/lane global->LDS DMA (wave-uniform LDS base + lane*16)
__device__ __forceinline__ void load16_lds(const void* g, void* l) {
  __builtin_amdgcn_global_load_lds(
      (const __attribute__((address_space(1))) unsigned int*)g,
      (__attribute__((address_space(3))) unsigned int*)l,
      16, 0, 0);
}

__device__ __forceinline__ unsigned short f2bf(float f) {
  bf16 h = __float2bfloat16(f);
  return __builtin_bit_cast(unsigned short, h);
}
__device__ __forceinline__ float bf2f(unsigned short u) {
  unsigned int i = ((unsigned int)u) << 16;
  return __builtin_bit_cast(float, i);
}

// ---------------------------------------------------------------------------
// Zero the grid-barrier counters (workspace is re-poisoned before each call)
// ---------------------------------------------------------------------------
__global__ __launch_bounds__(64) void init_ctr_kernel(unsigned int* ctrs) {
  if (threadIdx.x < 4) ctrs[threadIdx.x] = 0u;
}

// ---------------------------------------------------------------------------
// Embedding + sinusoidal positional concat; writes fp32 x and bf16 mirror xb
// ---------------------------------------------------------------------------
__global__ __launch_bounds__(512) void embed_pos_kernel(
    const int* __restrict__ tokens, const float* __restrict__ emb,
    float* __restrict__ x, bf16* __restrict__ xb)
{
  int bt = blockIdx.x;          // b*T + t
  int t  = bt & (T_ - 1);
  int j  = threadIdx.x;
  float val;
  if (j < 256) {
    int tok = tokens[bt];
    val = emb[tok * 256 + j];
  } else {
    int jj = (j - 256) & 127;
    float f = expf(-(float)(2 * jj) * (9.210340371976184f / 256.0f));
    float arg = (float)t * f;
    val = (j < 384) ? sinf(arg) : cosf(arg);
  }
  size_t off = (size_t)bt * D_ + j;
  x[off]  = val;
  xb[off] = __float2bfloat16(val);
}

// ---------------------------------------------------------------------------
// All weight transposes (Wv, WU, WV, Wout) + rf_fold_b in ONE launch.
// ---------------------------------------------------------------------------
__global__ __launch_bounds__(256) void prep_all_kernel(
    const float* __restrict__ Wv, const float* __restrict__ WU,
    const float* __restrict__ WVp, const float* __restrict__ Wout,
    bf16* __restrict__ WvT, bf16* __restrict__ WUT,
    bf16* __restrict__ WVT, bf16* __restrict__ WoutT,
    const float* __restrict__ bq, const float* __restrict__ bk,
    const float* __restrict__ rfs, float* __restrict__ bqf,
    float* __restrict__ bkf)
{
  __shared__ float t[32][33];
  int id = blockIdx.x;
  if (id >= 4736) {                 // rf_fold_b, z = id - 4736
    int z = id - 4736;
    int l = z >> 1, side = z & 1;
    const float* b = (side ? bk : bq) + l * D_;
    float* bo = (side ? bkf : bqf) + l * D_;
    for (int n = threadIdx.x; n < D_; n += 256) {
      int h = n >> 6, j = n & 63;
      const float* R = rfs + ((size_t)l * H_ + h) * 4096;
      float acc = 0.f;
      for (int d = 0; d < 64; ++d) acc += b[h * 64 + d] * R[d * 64 + j];
      bo[n] = acc * 0.35355339059327373f;
    }
    return;
  }
  const float* W; bf16* Wt; int K, N, tx, ty;
  if (id < 512) {                   // Wv
    int l = id >> 8, tt = id & 255;
    W = Wv + (size_t)l * D_ * D_;  Wt = WvT + (size_t)l * D_ * D_;
    K = D_; N = D_; tx = tt & 15; ty = tt >> 4;
  } else if (id < 2560) {           // WU
    int tt = id - 512; int l = tt >> 10; tt &= 1023;
    W = WU + (size_t)l * D_ * FFN_;  Wt = WUT + (size_t)l * D_ * FFN_;
    K = D_; N = FFN_; tx = tt & 63; ty = tt >> 6;
  } else if (id < 4608) {           // WV
    int tt = id - 2560; int l = tt >> 10; tt &= 1023;
    W = WVp + (size_t)l * FFN_ * D_;  Wt = WVT + (size_t)l * FFN_ * D_;
    K = FFN_; N = D_; tx = tt & 15; ty = tt >> 4;
  } else {                          // Wout
    int tt = id - 4608;
    W = Wout;  Wt = WoutT;
    K = D_; N = VOCAB_; tx = tt & 7; ty = tt >> 3;
  }
  int n0 = tx * 32, k0 = ty * 32;
  int lx = threadIdx.x & 31, ly = threadIdx.x >> 5;
#pragma unroll
  for (int r = 0; r < 4; ++r)
    t[ly + 8 * r][lx] = W[(size_t)(k0 + ly + 8 * r) * N + n0 + lx];
  __syncthreads();
#pragma unroll
  for (int r = 0; r < 4; ++r)
    Wt[(size_t)(n0 + ly + 8 * r) * K + k0 + lx] = __float2bfloat16(t[lx][ly + 8 * r]);
}

// ---------------------------------------------------------------------------
// RF-fold weights (grid (8,4,4))
// ---------------------------------------------------------------------------
__global__ __launch_bounds__(256) void rf_fold_w_kernel(
    const float* __restrict__ Wq, const float* __restrict__ Wk,
    const float* __restrict__ rfs, bf16* __restrict__ WqT, bf16* __restrict__ WkT)
{
  int h = blockIdx.x, kq = blockIdx.y, z = blockIdx.z;
  int l = z >> 1, side = z & 1;
  const float* W = (side ? Wk : Wq) + (size_t)l * D_ * D_;
  bf16* WT = (side ? WkT : WqT) + (size_t)l * D_ * D_;
  const float* Rg = rfs + ((size_t)l * H_ + h) * 4096;
  __shared__ float Rl[64][65];
  __shared__ float Ws[128][65];
  int tid = threadIdx.x;
  for (int i = tid; i < 1024; i += 256) {
    float4 v4 = ((const float4*)Rg)[i];
    int d = i >> 4, j0 = (i & 15) * 4;
    Rl[d][j0] = v4.x; Rl[d][j0+1] = v4.y; Rl[d][j0+2] = v4.z; Rl[d][j0+3] = v4.w;
  }
  for (int i = tid; i < 2048; i += 256) {
    int r = i >> 4, c0 = (i & 15) * 4;
    float4 v4 = *(const float4*)&W[(size_t)(kq * 128 + r) * D_ + h * 64 + c0];
    Ws[r][c0] = v4.x; Ws[r][c0+1] = v4.y; Ws[r][c0+2] = v4.z; Ws[r][c0+3] = v4.w;
  }
  __syncthreads();
  int lane = tid & 63, w = tid >> 6;
  for (int kh = 0; kh < 2; ++kh) {
    int kk = kh * 64 + lane;
#pragma unroll 1
    for (int jj = 0; jj < 16; ++jj) {
      int j = w * 16 + jj;
      float acc = 0.f;
#pragma unroll 16
      for (int d = 0; d < 64; ++d) acc += Ws[kk][d] * Rl[d][j];
      WT[(size_t)(h * 64 + j) * D_ + kq * 128 + kk] =
          __float2bfloat16(acc * 0.35355339059327373f);
    }
  }
}

// ---------------------------------------------------------------------------
// MFMA GEMM core: 128x128 tile, BK=64, XOR-swizzled LDS, DMA staging.
// ---------------------------------------------------------------------------
__device__ __forceinline__ void mfma_core(
    const bf16* __restrict__ A, const bf16* __restrict__ Bt,
    int strideK, int kr, int row0, int col0, float4v acc[4][4])
{
  __shared__ short Al[128 * 64];
  __shared__ short Bl[128 * 64];
  int tid = threadIdx.x;
  int lane = tid & 63, w = tid >> 6;
  int wm = (w >> 1) * 64, wn = (w & 1) * 64;
  int quad = lane >> 4, l16 = lane & 15;

  int lr = lane >> 3;
  int ks = (((lane & 7) ^ lr)) * 8;
  const short* gA[4]; const short* gB[4];
  short* lA[4]; short* lB[4];
#pragma unroll
  for (int p = 0; p < 4; ++p) {
    int r = 32 * w + 8 * p;
    gA[p] = (const short*)A + (size_t)(row0 + r + lr) * strideK + ks;
    gB[p] = (const short*)Bt + (size_t)(col0 + r + lr) * strideK + ks;
    lA[p] = Al + r * 64;
    lB[p] = Bl + r * 64;
  }
#pragma unroll
  for (int p = 0; p < 4; ++p) {
    load16_lds(gA[p], lA[p]);
    load16_lds(gB[p], lB[p]);
  }

  for (int kt = 0; kt < kr; ++kt) {
    __syncthreads();
    short8 af[4][2], bfr[4][2];
#pragma unroll
    for (int mi = 0; mi < 4; ++mi) {
      int R = wm + mi * 16 + l16;
#pragma unroll
      for (int s = 0; s < 2; ++s) {
        int slot = (s * 4 + quad) ^ (R & 7);
        af[mi][s] = *(const short8*)&Al[R * 64 + slot * 8];
      }
    }
#pragma unroll
    for (int ni = 0; ni < 4; ++ni) {
      int R = wn + ni * 16 + l16;
#pragma unroll
      for (int s = 0; s < 2; ++s) {
        int slot = (s * 4 + quad) ^ (R & 7);
        bfr[ni][s] = *(const short8*)&Bl[R * 64 + slot * 8];
      }
    }
    __syncthreads();
    if (kt + 1 < kr) {
      int o = (kt + 1) * 64;
#pragma unroll
      for (int p = 0; p < 4; ++p) {
        load16_lds(gA[p] + o, lA[p]);
        load16_lds(gB[p] + o, lB[p]);
      }
    }
#pragma unroll
    for (int mi = 0; mi < 4; ++mi)
#pragma unroll
      for (int ni = 0; ni < 4; ++ni) {
        acc[mi][ni] = __builtin_amdgcn_mfma_f32_16x16x32_bf16(
            af[mi][0], bfr[ni][0], acc[mi][ni], 0, 0, 0);
        acc[mi][ni] = __builtin_amdgcn_mfma_f32_16x16x32_bf16(
            af[mi][1], bfr[ni][1], acc[mi][ni], 0, 0, 0);
      }
  }
}

// ---------------------------------------------------------------------------
// Generic GEMM: C = act(A @ Bt^T + bias). mode 0: fp32. mode 1: gelu->bf16.
// Grid: (M/128, N/128) — row tile on blockIdx.x so same-row blocks share XCD.
// ---------------------------------------------------------------------------
__global__ __launch_bounds__(256) void gemm_mfma(
    const bf16* __restrict__ A, const bf16* __restrict__ Bt,
    const float* __restrict__ bias, void* __restrict__ Cout,
    int M, int N, int K, int mode)
{
  int lane = threadIdx.x & 63, w = threadIdx.x >> 6;
  int wm = (w >> 1) * 64, wn = (w & 1) * 64;
  int quad = lane >> 4, l16 = lane & 15;
  int row0 = blockIdx.x * 128, col0 = blockIdx.y * 128;
  float4v acc[4][4] = {};
  mfma_core(A, Bt, K, K >> 6, row0, col0, acc);
#pragma unroll
  for (int mi = 0; mi < 4; ++mi) {
#pragma unroll
    for (int ni = 0; ni < 4; ++ni) {
      int j = col0 + wn + ni * 16 + l16;
      float bj = bias[j];
#pragma unroll
      for (int r = 0; r < 4; ++r) {
        int i = row0 + wm + mi * 16 + quad * 4 + r;
        float v = acc[mi][ni][r] + bj;
        if (mode == 1) {
          v = 0.5f * v * (1.0f + erff(v * 0.7071067811865475f));
          ((bf16*)Cout)[(size_t)i * N + j] = __float2bfloat16(v);
        } else {
          ((float*)Cout)[(size_t)i * N + j] = v;
        }
      }
    }
  }
}

// ---------------------------------------------------------------------------
// Batched QKV GEMM with fused FAVOR exp for q,k: blockIdx.z = {q,k,v}.
// ---------------------------------------------------------------------------
__global__ __launch_bounds__(256) void gemm_qkv(
    const bf16* __restrict__ A, const bf16* __restrict__ wT,
    const float* __restrict__ bqf, const float* __restrict__ bkf,
    const float* __restrict__ bv, bf16* __restrict__ outb, int l)
{
  int z = blockIdx.z;
  const bf16* Bt = wT + ((size_t)z * 2 + l) * D_ * D_;
  const float* bias = (z == 0 ? bqf : (z == 1 ? bkf : bv)) + l * D_;
  bf16* Cout = outb + (size_t)z * BT_ * D_;
  int lane = threadIdx.x & 63, w = threadIdx.x >> 6;
  int wm = (w >> 1) * 64, wn = (w & 1) * 64;
  int quad = lane >> 4, l16 = lane & 15;
  int row0 = blockIdx.x * 128, col0 = blockIdx.y * 128;
  float4v acc[4][4] = {};
  mfma_core(A, Bt, D_, D_ >> 6, row0, col0, acc);
  if (z < 2) {
#pragma unroll
    for (int mi = 0; mi < 4; ++mi) {
      float vres[4][4];
      float sq[4] = {0.f, 0.f, 0.f, 0.f};
#pragma unroll
      for (int ni = 0; ni < 4; ++ni) {
        int j = col0 + wn + ni * 16 + l16;
        float bj = bias[j];
#pragma unroll
        for (int r = 0; r < 4; ++r) {
          float v = acc[mi][ni][r] + bj;
          vres[ni][r] = v;
          sq[r] += v * v;
        }
      }
#pragma unroll
      for (int r = 0; r < 4; ++r) {
        float s = sq[r];
        s += __shfl_xor(s, 1, 64);
        s += __shfl_xor(s, 2, 64);
        s += __shfl_xor(s, 4, 64);
        s += __shfl_xor(s, 8, 64);
        sq[r] = s;
      }
#pragma unroll
      for (int ni = 0; ni < 4; ++ni) {
        int j = col0 + wn + ni * 16 + l16;
#pragma unroll
        for (int r = 0; r < 4; ++r) {
          int i = row0 + wm + mi * 16 + quad * 4 + r;
          Cout[(size_t)i * D_ + j] =
              __float2bfloat16(__expf(vres[ni][r] - sq[r] * (1.0f / 128.0f)));
        }
      }
    }
  } else {
#pragma unroll
    for (int mi = 0; mi < 4; ++mi) {
#pragma unroll
      for (int ni = 0; ni < 4; ++ni) {
        int j = col0 + wn + ni * 16 + l16;
        float bj = bias[j];
#pragma unroll
        for (int r = 0; r < 4; ++r) {
          int i = row0 + wm + mi * 16 + quad * 4 + r;
          Cout[(size_t)i * D_ + j] = __float2bfloat16(acc[mi][ni][r] + bj);
        }
      }
    }
  }
}

// ---------------------------------------------------------------------------
// Split-K GEMM: P[s][M][N] = A[:, s*KS:(s+1)*KS] @ slice. s = blockIdx.z.
// ---------------------------------------------------------------------------
__global__ __launch_bounds__(256) void gemm_splitk(
    const bf16* __restrict__ A, const bf16* __restrict__ Bt,
    float* __restrict__ P, int M, int N, int K, int KS)
{
  int s = blockIdx.z;
  int lane = threadIdx.x & 63, w = threadIdx.x >> 6;
  int wm = (w >> 1) * 64, wn = (w & 1) * 64;
  int quad = lane >> 4, l16 = lane & 15;
  int row0 = blockIdx.x * 128, col0 = blockIdx.y * 128;
  float4v acc[4][4] = {};
  mfma_core((const bf16*)((const short*)A + s * KS),
            (const bf16*)((const short*)Bt + s * KS),
            K, KS >> 6, row0, col0, acc);
  float* Ps = P + (size_t)s * M * N;
#pragma unroll
  for (int mi = 0; mi < 4; ++mi) {
#pragma unroll
    for (int ni = 0; ni < 4; ++ni) {
      int j = col0 + wn + ni * 16 + l16;
#pragma unroll
      for (int r = 0; r < 4; ++r) {
        int i = row0 + wm + mi * 16 + quad * 4 + r;
        Ps[(size_t)i * N + j] = acc[mi][ni][r];
      }
    }
  }
}

// ---------------------------------------------------------------------------
// Final-output reduce: C = bias + sum of 4 split partials
// ---------------------------------------------------------------------------
__global__ __launch_bounds__(256) void reduce4_bias_kernel(
    const float* __restrict__ P, const float* __restrict__ bias,
    float* __restrict__ C, int MN, int N)
{
  int idx = (blockIdx.x * 256 + threadIdx.x) * 4;
  float4 s0 = *(const float4*)&P[idx];
  float4 s1 = *(const float4*)&P[idx + MN];
  float4 s2 = *(const float4*)&P[idx + 2 * MN];
  float4 s3 = *(const float4*)&P[idx + 3 * MN];
  float4 b  = *(const float4*)&bias[idx & (N - 1)];
  float4 r;
  r.x = s0.x + s1.x + s2.x + s3.x + b.x;
  r.y = s0.y + s1.y + s2.y + s3.y + b.y;
  r.z = s0.z + s1.z + s2.z + s3.z + b.z;
  r.w = s0.w + s1.w + s2.w + s3.w + b.w;
  *(float4*)&C[idx] = r;
}

// ---------------------------------------------------------------------------
// Fused split-K reduce + bias + LayerNorm + residual add (FFN2 epilogue)
// ---------------------------------------------------------------------------
__global__ __launch_bounds__(256) void reduce_ln_add_kernel(
    const float* __restrict__ P, const float* __restrict__ bias,
    float* __restrict__ x, bf16* __restrict__ xb,
    const float* __restrict__ g, const float* __restrict__ bta)
{
  const int MN = BT_ * D_;
  int row = blockIdx.x;
  int tid = threadIdx.x;
  size_t base = (size_t)row * D_;
  float v0 = P[base + tid] + P[MN + base + tid] + P[2 * MN + base + tid]
           + P[3 * MN + base + tid] + bias[tid];
  float v1 = P[base + tid + 256] + P[MN + base + tid + 256]
           + P[2 * MN + base + tid + 256] + P[3 * MN + base + tid + 256]
           + bias[tid + 256];
  __shared__ float red[4];
  float w = v0 + v1;
  for (int o = 32; o > 0; o >>= 1) w += __shfl_down(w, o, 64);
  if ((tid & 63) == 0) red[tid >> 6] = w;
  __syncthreads();
  float mu = (red[0] + red[1] + red[2] + red[3]) * (1.f / 512.f);
  float d0 = v0 - mu, d1 = v1 - mu;
  __syncthreads();
  w = d0 * d0 + d1 * d1;
  for (int o = 32; o > 0; o >>= 1) w += __shfl_down(w, o, 64);
  if ((tid & 63) == 0) red[tid >> 6] = w;
  __syncthreads();
  float var = (red[0] + red[1] + red[2] + red[3]) * (1.f / 512.f);
  float rs = rsqrtf(var + 1e-5f);
  float n0 = x[base + tid]       + d0 * rs * g[tid]       + bta[tid];
  float n1 = x[base + tid + 256] + d1 * rs * g[tid + 256] + bta[tid + 256];
  x[base + tid]        = n0;
  x[base + tid + 256]  = n1;
  xb[base + tid]       = __float2bfloat16(n0);
  xb[base + tid + 256] = __float2bfloat16(n1);
}

// ---------------------------------------------------------------------------
// Device-scope grid barrier. All 512 blocks are guaranteed co-resident:
// 34.5 KB LDS -> 4 blocks/CU, 256 thr -> 8 blocks/CU; capacity >= 1024.
// ---------------------------------------------------------------------------
__device__ __forceinline__ void grid_barrier(unsigned int* ctr, unsigned int n) {
  __syncthreads();
  __threadfence();
  if (threadIdx.x == 0) {
    atomicAdd(ctr, 1u);
    while (atomicAdd(ctr, 0u) < n) {}
  }
  __syncthreads();
  __threadfence();
}

// ---------------------------------------------------------------------------
// Fused attention: chunk sums + prefix scan + per-chunk attention in ONE
// launch (512 blocks = 16 bh x 32 chunks), manual grid barriers.
// Q/K/V staged once in LDS and retained across phases; S0T reuses KT space.
// ---------------------------------------------------------------------------
__global__ __launch_bounds__(256) void attn_mega_kernel(
    const bf16* __restrict__ qf, const bf16* __restrict__ kf,
    const bf16* __restrict__ vf, float* __restrict__ buf,
    float* __restrict__ out, unsigned int* __restrict__ ctr)
{
  int id = blockIdx.x;
  int bh = id >> 5, ck = id & 31;
  int b = bh >> 3, h = bh & 7;
  __shared__ short Qs[4096];   // [t][m] natural swizzled
  __shared__ short Ks[4096];   // [t][m]; reused as As[i][j] in phase C
  __shared__ short KT[4096];   // [m][t]; reused as S0T[d][m] in phase C
  __shared__ short VT[4096];   // [d][t]
  __shared__ float z0[64], dlds[64], dpartA[64], dpartQ[4][64];
  int tid = threadIdx.x;
  int lane = tid & 63, w = tid >> 6;
  int quad = lane >> 4, l16 = lane & 15;
  const size_t rb = ((size_t)(b * T_ + ck * 64)) * D_ + h * 64;

  // --- staging (once) ---
  {
    int lr = lane >> 3;
    int fc = (lane & 7) ^ lr;
#pragma unroll
    for (int seg = 0; seg < 2; ++seg) {
      int r = 16 * w + 8 * seg;
      load16_lds((const short*)qf + rb + (size_t)(r + lr) * D_ + fc * 8, &Qs[r * 64]);
      load16_lds((const short*)kf + rb + (size_t)(r + lr) * D_ + fc * 8, &Ks[r * 64]);
    }
    int m = lane;
#pragma unroll
    for (int cc0 = 0; cc0 < 2; ++cc0) {
      int cc = w + cc0 * 4;
      short8 kk, vv;
#pragma unroll
      for (int u = 0; u < 8; ++u) {
        size_t off = rb + (size_t)(cc * 8 + u) * D_ + m;
        kk[u] = ((const short*)kf)[off];
        vv[u] = ((const short*)vf)[off];
      }
      int slot = cc ^ (m & 7);
      *(short8*)&KT[m * 64 + slot * 8] = kk;
      *(short8*)&VT[m * 64 + slot * 8] = vv;
    }
  }
  __syncthreads();

  // --- phase A: chunk sums S_ck (ck < 31) ---
  if (ck < 31) {
    int ar = w * 16 + l16;
    short8 afr[2];
#pragma unroll
    for (int s = 0; s < 2; ++s)
      afr[s] = *(const short8*)&KT[ar * 64 + ((s * 4 + quad) ^ (ar & 7)) * 8];
    float4v sacc[4] = {};
#pragma unroll
    for (int nd = 0; nd < 4; ++nd) {
      int br = nd * 16 + l16;
#pragma unroll
      for (int s = 0; s < 2; ++s) {
        short8 bfr = *(const short8*)&VT[br * 64 + ((s * 4 + quad) ^ (br & 7)) * 8];
        sacc[nd] = __builtin_amdgcn_mfma_f32_16x16x32_bf16(afr[s], bfr, sacc[nd], 0, 0, 0);
      }
    }
    // z partials from KT
    int m = lane;
    float zp = 0.f;
#pragma unroll
    for (int cc0 = 0; cc0 < 2; ++cc0) {
      int cc = w + cc0 * 4;
      short8 kk = *(const short8*)&KT[m * 64 + (cc ^ (m & 7)) * 8];
#pragma unroll
      for (int u = 0; u < 8; ++u) zp += bf2f((unsigned short)kk[u]);
    }
    dpartQ[w][m] = zp;
    size_t bo = (size_t)(bh * 31 + ck) * CENT_;
#pragma unroll
    for (int nd = 0; nd < 4; ++nd)
#pragma unroll
      for (int r = 0; r < 4; ++r)
        buf[bo + (size_t)(w * 16 + quad * 4 + r) * 64 + nd * 16 + l16] = sacc[nd][r];
    __syncthreads();
    if (tid < 64)
      buf[bo + 4096 + tid] = dpartQ[0][tid] + dpartQ[1][tid]
                           + dpartQ[2][tid] + dpartQ[3][tid];
  }

  grid_barrier(&ctr[0], 512u);

  // --- phase B: inclusive prefix over 31 chunk states (blocks 0..259) ---
  if (id < 260) {
    int e = id * 256 + tid;          // 0 .. 66559 == 16*CENT_-1
    int pbh = e / CENT_, pe = e % CENT_;
    size_t base = (size_t)pbh * 31 * CENT_ + pe;
    float vals[31];
#pragma unroll
    for (int c = 0; c < 31; ++c) vals[c] = buf[base + (size_t)c * CENT_];
    float run = 0.f;
#pragma unroll
    for (int c = 0; c < 31; ++c) {
      run += vals[c];
      buf[base + (size_t)c * CENT_] = run;
    }
  }

  grid_barrier(&ctr[1], 512u);

  // --- phase C: per-chunk attention ---
  const float* S0 = buf + (size_t)(bh * 31 + (ck > 0 ? ck - 1 : 0)) * CENT_;
  {
    int d = lane;
#pragma unroll
    for (int cc0 = 0; cc0 < 2; ++cc0) {
      int cc = w + cc0 * 4;
      short8 ss;
#pragma unroll
      for (int u = 0; u < 8; ++u)
        ss[u] = (ck > 0) ? (short)f2bf(S0[(size_t)(cc * 8 + u) * 64 + d]) : (short)0;
      *(short8*)&KT[d * 64 + (cc ^ (d & 7)) * 8] = ss;   // KT now = S0T
    }
    if (tid < 64) z0[tid] = (ck > 0) ? S0[4096 + tid] : 0.f;
  }
  __syncthreads();

  // phase C1: A[i][j] = sum_m Qf[i][m] Kf[j][m]
  float4v pacc[4] = {};
  {
    int ar = 16 * w + l16;
    short8 afr[2];
#pragma unroll
    for (int s = 0; s < 2; ++s)
      afr[s] = *(const short8*)&Qs[ar * 64 + ((s * 4 + quad) ^ (ar & 7)) * 8];
#pragma unroll
    for (int nj = 0; nj < 4; ++nj) {
      int br = nj * 16 + l16;
#pragma unroll
      for (int s = 0; s < 2; ++s) {
        short8 bfr = *(const short8*)&Ks[br * 64 + ((s * 4 + quad) ^ (br & 7)) * 8];
        pacc[nj] = __builtin_amdgcn_mfma_f32_16x16x32_bf16(afr[s], bfr, pacc[nj], 0, 0, 0);
      }
    }
  }
  // den partial: qz[i] over m-chunks {w, w+4}
  {
    int i = lane;
    float qz = 0.f;
#pragma unroll
    for (int cc0 = 0; cc0 < 2; ++cc0) {
      int cc = w + cc0 * 4;
      short8 qq = *(const short8*)&Qs[i * 64 + (cc ^ (i & 7)) * 8];
#pragma unroll
      for (int u = 0; u < 8; ++u) qz += bf2f((unsigned short)qq[u]) * z0[cc * 8 + u];
    }
    dpartQ[w][i] = qz;
  }
  __syncthreads();               // all Ks frag reads done

  // mask + rowsum + write masked A (bf16) into Ks
  {
    float rs[4] = {0.f, 0.f, 0.f, 0.f};
#pragma unroll
    for (int nj = 0; nj < 4; ++nj) {
#pragma unroll
      for (int r = 0; r < 4; ++r) {
        int i = 16 * w + quad * 4 + r;
        int j = nj * 16 + l16;
        float val = (j <= i) ? pacc[nj][r] : 0.f;
        rs[r] += val;
        ((unsigned short*)Ks)[i * 64 + ((j >> 3) ^ (i & 7)) * 8 + (j & 7)] = f2bf(val);
      }
    }
#pragma unroll
    for (int r = 0; r < 4; ++r) {
      float s = rs[r];
      s += __shfl_xor(s, 1, 64);
      s += __shfl_xor(s, 2, 64);
      s += __shfl_xor(s, 4, 64);
      s += __shfl_xor(s, 8, 64);
      rs[r] = s;
    }
    if (l16 == 0) {
#pragma unroll
      for (int r = 0; r < 4; ++r) dpartA[16 * w + quad * 4 + r] = rs[r];
    }
  }
  __syncthreads();
  if (tid < 64)
    dlds[tid] = dpartA[tid] + dpartQ[0][tid] + dpartQ[1][tid]
              + dpartQ[2][tid] + dpartQ[3][tid];

  // phase C2: num = As.V + Qf.S0
  float4v acc[4] = {};
  {
    int ar = 16 * w + l16;
    short8 aA[2], aQ[2];
#pragma unroll
    for (int s = 0; s < 2; ++s) {
      aA[s] = *(const short8*)&Ks[ar * 64 + ((s * 4 + quad) ^ (ar & 7)) * 8];
      aQ[s] = *(const short8*)&Qs[ar * 64 + ((s * 4 + quad) ^ (ar & 7)) * 8];
    }
#pragma unroll
    for (int nd = 0; nd < 4; ++nd) {
      int br = nd * 16 + l16;
#pragma unroll
      for (int s = 0; s < 2; ++s) {
        short8 bV = *(const short8*)&VT[br * 64 + ((s * 4 + quad) ^ (br & 7)) * 8];
        acc[nd] = __builtin_amdgcn_mfma_f32_16x16x32_bf16(aA[s], bV, acc[nd], 0, 0, 0);
        short8 bS = *(const short8*)&KT[br * 64 + ((s * 4 + quad) ^ (br & 7)) * 8];
        acc[nd] = __builtin_amdgcn_mfma_f32_16x16x32_bf16(aQ[s], bS, acc[nd], 0, 0, 0);
      }
    }
  }
  __syncthreads();               // dlds visible
#pragma unroll
  for (int nd = 0; nd < 4; ++nd)
#pragma unroll
    for (int r = 0; r < 4; ++r) {
      int i = 16 * w + quad * 4 + r;
      int d = nd * 16 + l16;
      out[((size_t)(b * T_ + ck * 64 + i)) * D_ + h * 64 + d] =
          acc[nd][r] / (dlds[i] + 1e-16f);
    }
}

// ---------------------------------------------------------------------------
// x[row,:] += LayerNorm(a[row,:]) * g + b ; also writes bf16 mirror xb
// ---------------------------------------------------------------------------
__global__ __launch_bounds__(256) void ln_add_kernel(
    float* __restrict__ x, bf16* __restrict__ xb, const float* __restrict__ a,
    const float* __restrict__ g, const float* __restrict__ bta)
{
  int row = blockIdx.x;
  int tid = threadIdx.x;
  const float* ar = a + (size_t)row * D_;
  float v0 = ar[tid], v1 = ar[tid + 256];
  __shared__ float red[4];
  float w = v0 + v1;
  for (int o = 32; o > 0; o >>= 1) w += __shfl_down(w, o, 64);
  if ((tid & 63) == 0) red[tid >> 6] = w;
  __syncthreads();
  float mu = (red[0] + red[1] + red[2] + red[3]) * (1.f / 512.f);
  float d0 = v0 - mu, d1 = v1 - mu;
  __syncthreads();
  w = d0 * d0 + d1 * d1;
  for (int o = 32; o > 0; o >>= 1) w += __shfl_down(w, o, 64);
  if ((tid & 63) == 0) red[tid >> 6] = w;
  __syncthreads();
  float var = (red[0] + red[1] + red[2] + red[3]) * (1.f / 512.f);
  float rs = rsqrtf(var + 1e-5f);
  size_t xoff = (size_t)row * D_;
  float n0 = x[xoff + tid]       + d0 * rs * g[tid]       + bta[tid];
  float n1 = x[xoff + tid + 256] + d1 * rs * g[tid + 256] + bta[tid + 256];
  x[xoff + tid]        = n0;
  x[xoff + tid + 256]  = n1;
  xb[xoff + tid]       = __float2bfloat16(n0);
  xb[xoff + tid + 256] = __float2bfloat16(n1);
}

// ---------------------------------------------------------------------------
extern "C" void kernel_launch(void* const* d_in, const int* in_sizes, int n_in,
                              void* d_out, int out_size, void* d_ws, size_t ws_size,
                              hipStream_t stream) {
  const int*   tokens = (const int*)  d_in[0];
  const float* emb    = (const float*)d_in[1];
  const float* Wq     = (const float*)d_in[2];
  const float* bq     = (const float*)d_in[3];
  const float* Wk     = (const float*)d_in[4];
  const float* bk     = (const float*)d_in[5];
  const float* Wv     = (const float*)d_in[6];
  const float* bv     = (const float*)d_in[7];
  const float* rfs    = (const float*)d_in[8];
  const float* ln1g   = (const float*)d_in[9];
  const float* ln1b   = (const float*)d_in[10];
  const float* ln2g   = (const float*)d_in[11];
  const float* ln2b   = (const float*)d_in[12];
  const float* WU     = (const float*)d_in[13];
  const float* bU     = (const float*)d_in[14];
  const float* WV     = (const float*)d_in[15];
  const float* bV     = (const float*)d_in[16];
  const float* Wout   = (const float*)d_in[17];
  const float* bout   = (const float*)d_in[18];
  float* out = (float*)d_out;

  const size_t R = (size_t)BT_ * D_;          // 2,097,152 floats (8 MB)
  float* ws = (float*)d_ws;
  float* x  = ws;                             // [0, R)
  float* ab = ws + R;                         // [R, 2R)
  float* sb = ws + 2 * R;                     // [2R, 3R) chunk states (7.9 MB)
  bf16*  qb = (bf16*)(ws + 3 * R);            // [3R, 3.5R) bf16 BT x D
  bf16*  kb = (bf16*)(ws + 3 * R + R / 2);    // [3.5R, 4R)
  bf16*  vb = (bf16*)(ws + 4 * R);            // [4R, 4.5R)
  bf16*  xb = (bf16*)(ws + 4 * R + R / 2);    // [4.5R, 5R)
  bf16*  hb = (bf16*)(ws + 5 * R);            // [5R, 7R) bf16 BT x FFN
  float* pb = ws + 7 * R;                     // [7R, 11R) split-K partials
  bf16*  wT = (bf16*)(ws + 11 * R);           // weights
  bf16* WqT   = wT;                            // [L][D][D] (RF-folded)
  bf16* WkT   = WqT + (size_t)2 * D_ * D_;
  bf16* WvT   = WkT + (size_t)2 * D_ * D_;
  bf16* WUT   = WvT + (size_t)2 * D_ * D_;     // [L][FFN][D]
  bf16* WVT   = WUT + (size_t)2 * D_ * FFN_;   // [L][D][FFN]
  bf16* WoutT = WVT + (size_t)2 * D_ * FFN_;   // [VOCAB][D]
  float* bqf  = (float*)(WoutT + (size_t)VOCAB_ * D_);
  float* bkf  = bqf + 2 * D_;
  unsigned int* ctrs = (unsigned int*)(bkf + 2 * D_);  // 4 barrier counters

  // ---- prep ----
  init_ctr_kernel<<<1, 64, 0, stream>>>(ctrs);
  rf_fold_w_kernel<<<dim3(8, 4, 4), 256, 0, stream>>>(Wq, Wk, rfs, WqT, WkT);
  prep_all_kernel<<<4740, 256, 0, stream>>>(
      Wv, WU, WV, Wout, WvT, WUT, WVT, WoutT, bq, bk, rfs, bqf, bkf);

  embed_pos_kernel<<<BT_, 512, 0, stream>>>(tokens, emb, x, xb);

  for (int l = 0; l < 2; ++l) {
    gemm_qkv<<<dim3(BT_/128, D_/128, 3), 256, 0, stream>>>(
        xb, wT, bqf, bkf, bv, qb, l);

    attn_mega_kernel<<<16 * NC_, 256, 0, stream>>>(qb, kb, vb, sb, ab, ctrs + 2 * l);

    ln_add_kernel<<<BT_, 256, 0, stream>>>(x, xb, ab, ln1g + l*D_, ln1b + l*D_);

    gemm_mfma<<<dim3(BT_/128, FFN_/128), 256, 0, stream>>>(
        xb, WUT + (size_t)l*D_*FFN_, bU + l*FFN_, hb, BT_, FFN_, D_, 1);

    gemm_splitk<<<dim3(BT_/128, D_/128, 4), 256, 0, stream>>>(
        hb, WVT + (size_t)l*FFN_*D_, pb, BT_, D_, FFN_, FFN_/4);
    reduce_ln_add_kernel<<<BT_, 256, 0, stream>>>(
        pb, bV + l*D_, x, xb, ln2g + l*D_, ln2b + l*D_);
  }

  gemm_splitk<<<dim3(BT_/128, VOCAB_/128, 4), 256, 0, stream>>>(
      xb, WoutT, pb, BT_, VOCAB_, D_, D_/4);
  reduce4_bias_kernel<<<(BT_*VOCAB_)/1024, 256, 0, stream>>>(
      pb, bout, out, BT_*VOCAB_, VOCAB_);
}

// Round 14
// 320.927 us; speedup vs baseline: 2.2890x; 2.2890x over previous
//
#include <hip/hip_runtime.h>
#include <hip/hip_bf16.h>
#include <math.h>

#define B_  2
#define T_  2048
#define D_  512
#define H_  8
#define HD_ 64
#define FFN_ 2048
#define VOCAB_ 256
#define BT_ (B_*T_)
#define NC_ 32            // chunks per (b,h), chunk size 64
#define CENT_ 4160        // floats per chunk state: 64*64 S + 64 z

typedef __attribute__((ext_vector_type(8))) short short8;
typedef __attribute__((ext_vector_type(4))) float float4v;
typedef __hip_bfloat16 bf16;

// async 16B/lane global->LDS DMA (wave-uniform LDS base + lane*16)
__device__ __forceinline__ void load16_lds(const void* g, void* l) {
  __builtin_amdgcn_global_load_lds(
      (const __attribute__((address_space(1))) unsigned int*)g,
      (__attribute__((address_space(3))) unsigned int*)l,
      16, 0, 0);
}

__device__ __forceinline__ unsigned short f2bf(float f) {
  bf16 h = __float2bfloat16(f);
  return __builtin_bit_cast(unsigned short, h);
}
__device__ __forceinline__ float bf2f(unsigned short u) {
  unsigned int i = ((unsigned int)u) << 16;
  return __builtin_bit_cast(float, i);
}

// ---------------------------------------------------------------------------
// Embedding + sinusoidal positional concat; writes fp32 x and bf16 mirror xb
// ---------------------------------------------------------------------------
__global__ __launch_bounds__(512) void embed_pos_kernel(
    const int* __restrict__ tokens, const float* __restrict__ emb,
    float* __restrict__ x, bf16* __restrict__ xb)
{
  int bt = blockIdx.x;          // b*T + t
  int t  = bt & (T_ - 1);
  int j  = threadIdx.x;
  float val;
  if (j < 256) {
    int tok = tokens[bt];
    val = emb[tok * 256 + j];
  } else {
    int jj = (j - 256) & 127;
    float f = expf(-(float)(2 * jj) * (9.210340371976184f / 256.0f));
    float arg = (float)t * f;
    val = (j < 384) ? sinf(arg) : cosf(arg);
  }
  size_t off = (size_t)bt * D_ + j;
  x[off]  = val;
  xb[off] = __float2bfloat16(val);
}

// ---------------------------------------------------------------------------
// All weight transposes (Wv, WU, WV, Wout) + rf_fold_b in ONE launch.
// ---------------------------------------------------------------------------
__global__ __launch_bounds__(256) void prep_all_kernel(
    const float* __restrict__ Wv, const float* __restrict__ WU,
    const float* __restrict__ WVp, const float* __restrict__ Wout,
    bf16* __restrict__ WvT, bf16* __restrict__ WUT,
    bf16* __restrict__ WVT, bf16* __restrict__ WoutT,
    const float* __restrict__ bq, const float* __restrict__ bk,
    const float* __restrict__ rfs, float* __restrict__ bqf,
    float* __restrict__ bkf)
{
  __shared__ float t[32][33];
  int id = blockIdx.x;
  if (id >= 4736) {                 // rf_fold_b, z = id - 4736
    int z = id - 4736;
    int l = z >> 1, side = z & 1;
    const float* b = (side ? bk : bq) + l * D_;
    float* bo = (side ? bkf : bqf) + l * D_;
    for (int n = threadIdx.x; n < D_; n += 256) {
      int h = n >> 6, j = n & 63;
      const float* R = rfs + ((size_t)l * H_ + h) * 4096;
      float acc = 0.f;
      for (int d = 0; d < 64; ++d) acc += b[h * 64 + d] * R[d * 64 + j];
      bo[n] = acc * 0.35355339059327373f;
    }
    return;
  }
  const float* W; bf16* Wt; int K, N, tx, ty;
  if (id < 512) {                   // Wv
    int l = id >> 8, tt = id & 255;
    W = Wv + (size_t)l * D_ * D_;  Wt = WvT + (size_t)l * D_ * D_;
    K = D_; N = D_; tx = tt & 15; ty = tt >> 4;
  } else if (id < 2560) {           // WU
    int tt = id - 512; int l = tt >> 10; tt &= 1023;
    W = WU + (size_t)l * D_ * FFN_;  Wt = WUT + (size_t)l * D_ * FFN_;
    K = D_; N = FFN_; tx = tt & 63; ty = tt >> 6;
  } else if (id < 4608) {           // WV
    int tt = id - 2560; int l = tt >> 10; tt &= 1023;
    W = WVp + (size_t)l * FFN_ * D_;  Wt = WVT + (size_t)l * FFN_ * D_;
    K = FFN_; N = D_; tx = tt & 15; ty = tt >> 4;
  } else {                          // Wout
    int tt = id - 4608;
    W = Wout;  Wt = WoutT;
    K = D_; N = VOCAB_; tx = tt & 7; ty = tt >> 3;
  }
  int n0 = tx * 32, k0 = ty * 32;
  int lx = threadIdx.x & 31, ly = threadIdx.x >> 5;
#pragma unroll
  for (int r = 0; r < 4; ++r)
    t[ly + 8 * r][lx] = W[(size_t)(k0 + ly + 8 * r) * N + n0 + lx];
  __syncthreads();
#pragma unroll
  for (int r = 0; r < 4; ++r)
    Wt[(size_t)(n0 + ly + 8 * r) * K + k0 + lx] = __float2bfloat16(t[lx][ly + 8 * r]);
}

// ---------------------------------------------------------------------------
// RF-fold weights (grid (8,4,4))
// ---------------------------------------------------------------------------
__global__ __launch_bounds__(256) void rf_fold_w_kernel(
    const float* __restrict__ Wq, const float* __restrict__ Wk,
    const float* __restrict__ rfs, bf16* __restrict__ WqT, bf16* __restrict__ WkT)
{
  int h = blockIdx.x, kq = blockIdx.y, z = blockIdx.z;
  int l = z >> 1, side = z & 1;
  const float* W = (side ? Wk : Wq) + (size_t)l * D_ * D_;
  bf16* WT = (side ? WkT : WqT) + (size_t)l * D_ * D_;
  const float* Rg = rfs + ((size_t)l * H_ + h) * 4096;
  __shared__ float Rl[64][65];
  __shared__ float Ws[128][65];
  int tid = threadIdx.x;
  for (int i = tid; i < 1024; i += 256) {
    float4 v4 = ((const float4*)Rg)[i];
    int d = i >> 4, j0 = (i & 15) * 4;
    Rl[d][j0] = v4.x; Rl[d][j0+1] = v4.y; Rl[d][j0+2] = v4.z; Rl[d][j0+3] = v4.w;
  }
  for (int i = tid; i < 2048; i += 256) {
    int r = i >> 4, c0 = (i & 15) * 4;
    float4 v4 = *(const float4*)&W[(size_t)(kq * 128 + r) * D_ + h * 64 + c0];
    Ws[r][c0] = v4.x; Ws[r][c0+1] = v4.y; Ws[r][c0+2] = v4.z; Ws[r][c0+3] = v4.w;
  }
  __syncthreads();
  int lane = tid & 63, w = tid >> 6;
  for (int kh = 0; kh < 2; ++kh) {
    int kk = kh * 64 + lane;
#pragma unroll 1
    for (int jj = 0; jj < 16; ++jj) {
      int j = w * 16 + jj;
      float acc = 0.f;
#pragma unroll 16
      for (int d = 0; d < 64; ++d) acc += Ws[kk][d] * Rl[d][j];
      WT[(size_t)(h * 64 + j) * D_ + kq * 128 + kk] =
          __float2bfloat16(acc * 0.35355339059327373f);
    }
  }
}

// ---------------------------------------------------------------------------
// MFMA GEMM core: 128x128 tile, BK=64, XOR-swizzled LDS, DMA staging.
// ---------------------------------------------------------------------------
__device__ __forceinline__ void mfma_core(
    const bf16* __restrict__ A, const bf16* __restrict__ Bt,
    int strideK, int kr, int row0, int col0, float4v acc[4][4])
{
  __shared__ short Al[128 * 64];
  __shared__ short Bl[128 * 64];
  int tid = threadIdx.x;
  int lane = tid & 63, w = tid >> 6;
  int wm = (w >> 1) * 64, wn = (w & 1) * 64;
  int quad = lane >> 4, l16 = lane & 15;

  int lr = lane >> 3;
  int ks = (((lane & 7) ^ lr)) * 8;
  const short* gA[4]; const short* gB[4];
  short* lA[4]; short* lB[4];
#pragma unroll
  for (int p = 0; p < 4; ++p) {
    int r = 32 * w + 8 * p;
    gA[p] = (const short*)A + (size_t)(row0 + r + lr) * strideK + ks;
    gB[p] = (const short*)Bt + (size_t)(col0 + r + lr) * strideK + ks;
    lA[p] = Al + r * 64;
    lB[p] = Bl + r * 64;
  }
#pragma unroll
  for (int p = 0; p < 4; ++p) {
    load16_lds(gA[p], lA[p]);
    load16_lds(gB[p], lB[p]);
  }

  for (int kt = 0; kt < kr; ++kt) {
    __syncthreads();
    short8 af[4][2], bfr[4][2];
#pragma unroll
    for (int mi = 0; mi < 4; ++mi) {
      int R = wm + mi * 16 + l16;
#pragma unroll
      for (int s = 0; s < 2; ++s) {
        int slot = (s * 4 + quad) ^ (R & 7);
        af[mi][s] = *(const short8*)&Al[R * 64 + slot * 8];
      }
    }
#pragma unroll
    for (int ni = 0; ni < 4; ++ni) {
      int R = wn + ni * 16 + l16;
#pragma unroll
      for (int s = 0; s < 2; ++s) {
        int slot = (s * 4 + quad) ^ (R & 7);
        bfr[ni][s] = *(const short8*)&Bl[R * 64 + slot * 8];
      }
    }
    __syncthreads();
    if (kt + 1 < kr) {
      int o = (kt + 1) * 64;
#pragma unroll
      for (int p = 0; p < 4; ++p) {
        load16_lds(gA[p] + o, lA[p]);
        load16_lds(gB[p] + o, lB[p]);
      }
    }
#pragma unroll
    for (int mi = 0; mi < 4; ++mi)
#pragma unroll
      for (int ni = 0; ni < 4; ++ni) {
        acc[mi][ni] = __builtin_amdgcn_mfma_f32_16x16x32_bf16(
            af[mi][0], bfr[ni][0], acc[mi][ni], 0, 0, 0);
        acc[mi][ni] = __builtin_amdgcn_mfma_f32_16x16x32_bf16(
            af[mi][1], bfr[ni][1], acc[mi][ni], 0, 0, 0);
      }
  }
}

// ---------------------------------------------------------------------------
// Generic GEMM: C = act(A @ Bt^T + bias). mode 0: fp32. mode 1: gelu->bf16.
// Grid: (M/128, N/128) — row tile on blockIdx.x so same-row blocks share XCD.
// ---------------------------------------------------------------------------
__global__ __launch_bounds__(256) void gemm_mfma(
    const bf16* __restrict__ A, const bf16* __restrict__ Bt,
    const float* __restrict__ bias, void* __restrict__ Cout,
    int M, int N, int K, int mode)
{
  int lane = threadIdx.x & 63, w = threadIdx.x >> 6;
  int wm = (w >> 1) * 64, wn = (w & 1) * 64;
  int quad = lane >> 4, l16 = lane & 15;
  int row0 = blockIdx.x * 128, col0 = blockIdx.y * 128;
  float4v acc[4][4] = {};
  mfma_core(A, Bt, K, K >> 6, row0, col0, acc);
#pragma unroll
  for (int mi = 0; mi < 4; ++mi) {
#pragma unroll
    for (int ni = 0; ni < 4; ++ni) {
      int j = col0 + wn + ni * 16 + l16;
      float bj = bias[j];
#pragma unroll
      for (int r = 0; r < 4; ++r) {
        int i = row0 + wm + mi * 16 + quad * 4 + r;
        float v = acc[mi][ni][r] + bj;
        if (mode == 1) {
          v = 0.5f * v * (1.0f + erff(v * 0.7071067811865475f));
          ((bf16*)Cout)[(size_t)i * N + j] = __float2bfloat16(v);
        } else {
          ((float*)Cout)[(size_t)i * N + j] = v;
        }
      }
    }
  }
}

// ---------------------------------------------------------------------------
// Batched QKV GEMM with fused FAVOR exp for q,k: blockIdx.z = {q,k,v}.
// ---------------------------------------------------------------------------
__global__ __launch_bounds__(256) void gemm_qkv(
    const bf16* __restrict__ A, const bf16* __restrict__ wT,
    const float* __restrict__ bqf, const float* __restrict__ bkf,
    const float* __restrict__ bv, bf16* __restrict__ outb, int l)
{
  int z = blockIdx.z;
  const bf16* Bt = wT + ((size_t)z * 2 + l) * D_ * D_;
  const float* bias = (z == 0 ? bqf : (z == 1 ? bkf : bv)) + l * D_;
  bf16* Cout = outb + (size_t)z * BT_ * D_;
  int lane = threadIdx.x & 63, w = threadIdx.x >> 6;
  int wm = (w >> 1) * 64, wn = (w & 1) * 64;
  int quad = lane >> 4, l16 = lane & 15;
  int row0 = blockIdx.x * 128, col0 = blockIdx.y * 128;
  float4v acc[4][4] = {};
  mfma_core(A, Bt, D_, D_ >> 6, row0, col0, acc);
  if (z < 2) {
#pragma unroll
    for (int mi = 0; mi < 4; ++mi) {
      float vres[4][4];
      float sq[4] = {0.f, 0.f, 0.f, 0.f};
#pragma unroll
      for (int ni = 0; ni < 4; ++ni) {
        int j = col0 + wn + ni * 16 + l16;
        float bj = bias[j];
#pragma unroll
        for (int r = 0; r < 4; ++r) {
          float v = acc[mi][ni][r] + bj;
          vres[ni][r] = v;
          sq[r] += v * v;
        }
      }
#pragma unroll
      for (int r = 0; r < 4; ++r) {
        float s = sq[r];
        s += __shfl_xor(s, 1, 64);
        s += __shfl_xor(s, 2, 64);
        s += __shfl_xor(s, 4, 64);
        s += __shfl_xor(s, 8, 64);
        sq[r] = s;
      }
#pragma unroll
      for (int ni = 0; ni < 4; ++ni) {
        int j = col0 + wn + ni * 16 + l16;
#pragma unroll
        for (int r = 0; r < 4; ++r) {
          int i = row0 + wm + mi * 16 + quad * 4 + r;
          Cout[(size_t)i * D_ + j] =
              __float2bfloat16(__expf(vres[ni][r] - sq[r] * (1.0f / 128.0f)));
        }
      }
    }
  } else {
#pragma unroll
    for (int mi = 0; mi < 4; ++mi) {
#pragma unroll
      for (int ni = 0; ni < 4; ++ni) {
        int j = col0 + wn + ni * 16 + l16;
        float bj = bias[j];
#pragma unroll
        for (int r = 0; r < 4; ++r) {
          int i = row0 + wm + mi * 16 + quad * 4 + r;
          Cout[(size_t)i * D_ + j] = __float2bfloat16(acc[mi][ni][r] + bj);
        }
      }
    }
  }
}

// ---------------------------------------------------------------------------
// Split-K GEMM: P[s][M][N] = A[:, s*KS:(s+1)*KS] @ slice. s = blockIdx.z.
// ---------------------------------------------------------------------------
__global__ __launch_bounds__(256) void gemm_splitk(
    const bf16* __restrict__ A, const bf16* __restrict__ Bt,
    float* __restrict__ P, int M, int N, int K, int KS)
{
  int s = blockIdx.z;
  int lane = threadIdx.x & 63, w = threadIdx.x >> 6;
  int wm = (w >> 1) * 64, wn = (w & 1) * 64;
  int quad = lane >> 4, l16 = lane & 15;
  int row0 = blockIdx.x * 128, col0 = blockIdx.y * 128;
  float4v acc[4][4] = {};
  mfma_core((const bf16*)((const short*)A + s * KS),
            (const bf16*)((const short*)Bt + s * KS),
            K, KS >> 6, row0, col0, acc);
  float* Ps = P + (size_t)s * M * N;
#pragma unroll
  for (int mi = 0; mi < 4; ++mi) {
#pragma unroll
    for (int ni = 0; ni < 4; ++ni) {
      int j = col0 + wn + ni * 16 + l16;
#pragma unroll
      for (int r = 0; r < 4; ++r) {
        int i = row0 + wm + mi * 16 + quad * 4 + r;
        Ps[(size_t)i * N + j] = acc[mi][ni][r];
      }
    }
  }
}

// ---------------------------------------------------------------------------
// Final-output reduce: C = bias + sum of 4 split partials
// ---------------------------------------------------------------------------
__global__ __launch_bounds__(256) void reduce4_bias_kernel(
    const float* __restrict__ P, const float* __restrict__ bias,
    float* __restrict__ C, int MN, int N)
{
  int idx = (blockIdx.x * 256 + threadIdx.x) * 4;
  float4 s0 = *(const float4*)&P[idx];
  float4 s1 = *(const float4*)&P[idx + MN];
  float4 s2 = *(const float4*)&P[idx + 2 * MN];
  float4 s3 = *(const float4*)&P[idx + 3 * MN];
  float4 b  = *(const float4*)&bias[idx & (N - 1)];
  float4 r;
  r.x = s0.x + s1.x + s2.x + s3.x + b.x;
  r.y = s0.y + s1.y + s2.y + s3.y + b.y;
  r.z = s0.z + s1.z + s2.z + s3.z + b.z;
  r.w = s0.w + s1.w + s2.w + s3.w + b.w;
  *(float4*)&C[idx] = r;
}

// ---------------------------------------------------------------------------
// Fused split-K reduce + bias + LayerNorm + residual add (FFN2 epilogue)
// ---------------------------------------------------------------------------
__global__ __launch_bounds__(256) void reduce_ln_add_kernel(
    const float* __restrict__ P, const float* __restrict__ bias,
    float* __restrict__ x, bf16* __restrict__ xb,
    const float* __restrict__ g, const float* __restrict__ bta)
{
  const int MN = BT_ * D_;
  int row = blockIdx.x;
  int tid = threadIdx.x;
  size_t base = (size_t)row * D_;
  float v0 = P[base + tid] + P[MN + base + tid] + P[2 * MN + base + tid]
           + P[3 * MN + base + tid] + bias[tid];
  float v1 = P[base + tid + 256] + P[MN + base + tid + 256]
           + P[2 * MN + base + tid + 256] + P[3 * MN + base + tid + 256]
           + bias[tid + 256];
  __shared__ float red[4];
  float w = v0 + v1;
  for (int o = 32; o > 0; o >>= 1) w += __shfl_down(w, o, 64);
  if ((tid & 63) == 0) red[tid >> 6] = w;
  __syncthreads();
  float mu = (red[0] + red[1] + red[2] + red[3]) * (1.f / 512.f);
  float d0 = v0 - mu, d1 = v1 - mu;
  __syncthreads();
  w = d0 * d0 + d1 * d1;
  for (int o = 32; o > 0; o >>= 1) w += __shfl_down(w, o, 64);
  if ((tid & 63) == 0) red[tid >> 6] = w;
  __syncthreads();
  float var = (red[0] + red[1] + red[2] + red[3]) * (1.f / 512.f);
  float rs = rsqrtf(var + 1e-5f);
  float n0 = x[base + tid]       + d0 * rs * g[tid]       + bta[tid];
  float n1 = x[base + tid + 256] + d1 * rs * g[tid + 256] + bta[tid + 256];
  x[base + tid]        = n0;
  x[base + tid + 256]  = n1;
  xb[base + tid]       = __float2bfloat16(n0);
  xb[base + tid + 256] = __float2bfloat16(n1);
}

// ---------------------------------------------------------------------------
// Pass 1 (MFMA): per-chunk sums. S[m][d] = sum_t Kf[t][m] V[t][d].
// ---------------------------------------------------------------------------
__global__ __launch_bounds__(256) void chunk_sum_kernel(
    const bf16* __restrict__ kf, const bf16* __restrict__ vf,
    float* __restrict__ buf)
{
  int bh = blockIdx.x / 31;
  int c  = blockIdx.x % 31;
  int b = bh >> 3, h = bh & 7;
  __shared__ short KT[64 * 64];   // [m][t] swizzled
  __shared__ short VT[64 * 64];   // [d][t] swizzled
  __shared__ float zpart[4][64];
  int tid = threadIdx.x;
  int m = tid & 63, g = tid >> 6;
  const size_t rowbase = ((size_t)(b * T_ + c * 64)) * D_ + h * 64;
#pragma unroll
  for (int cc0 = 0; cc0 < 2; ++cc0) {
    int cc = g + cc0 * 4;
    short8 kk, vv;
#pragma unroll
    for (int u = 0; u < 8; ++u) {
      size_t off = rowbase + (size_t)(cc * 8 + u) * D_ + m;
      kk[u] = ((const short*)kf)[off];
      vv[u] = ((const short*)vf)[off];
    }
    int slot = cc ^ (m & 7);
    *(short8*)&KT[m * 64 + slot * 8] = kk;
    *(short8*)&VT[m * 64 + slot * 8] = vv;
  }
  __syncthreads();
  int quad = (tid & 63) >> 4, l16 = tid & 15;
  int ar = g * 16 + l16;          // A row (m), wave g band
  short8 afr[2];
#pragma unroll
  for (int s = 0; s < 2; ++s)
    afr[s] = *(const short8*)&KT[ar * 64 + ((s * 4 + quad) ^ (ar & 7)) * 8];
  float4v acc[4] = {};
#pragma unroll
  for (int nd = 0; nd < 4; ++nd) {
    int br = nd * 16 + l16;
#pragma unroll
    for (int s = 0; s < 2; ++s) {
      short8 bfr = *(const short8*)&VT[br * 64 + ((s * 4 + quad) ^ (br & 7)) * 8];
      acc[nd] = __builtin_amdgcn_mfma_f32_16x16x32_bf16(afr[s], bfr, acc[nd], 0, 0, 0);
    }
  }
  // z partials from KT
  float zp = 0.f;
#pragma unroll
  for (int cc0 = 0; cc0 < 2; ++cc0) {
    int cc = g + cc0 * 4;
    short8 kk = *(const short8*)&KT[m * 64 + (cc ^ (m & 7)) * 8];
#pragma unroll
    for (int u = 0; u < 8; ++u) zp += bf2f((unsigned short)kk[u]);
  }
  zpart[g][m] = zp;
  size_t bo = (size_t)(bh * 31 + c) * CENT_;
#pragma unroll
  for (int nd = 0; nd < 4; ++nd)
#pragma unroll
    for (int r = 0; r < 4; ++r)
      buf[bo + (size_t)(g * 16 + quad * 4 + r) * 64 + nd * 16 + l16] = acc[nd][r];
  __syncthreads();
  if (tid < 64)
    buf[bo + 4096 + tid] = zpart[0][tid] + zpart[1][tid] + zpart[2][tid] + zpart[3][tid];
}

// ---------------------------------------------------------------------------
// Pass 2: inclusive scan over 31 chunk states per (b,h)
// ---------------------------------------------------------------------------
__global__ __launch_bounds__(256) void chunk_prefix_kernel(float* __restrict__ buf)
{
  int bh = blockIdx.x / 17;
  int grp = blockIdx.x % 17;
  int e = grp * 256 + threadIdx.x;
  if (e >= CENT_) return;
  size_t base = (size_t)bh * 31 * CENT_ + e;
  float vals[31];
#pragma unroll
  for (int c = 0; c < 31; ++c) vals[c] = buf[base + (size_t)c * CENT_];
  float run = 0.f;
#pragma unroll
  for (int c = 0; c < 31; ++c) {
    run += vals[c];
    buf[base + (size_t)c * CENT_] = run;
  }
}

// ---------------------------------------------------------------------------
// Pass 3 (MFMA): per-chunk attention.
// ---------------------------------------------------------------------------
__global__ __launch_bounds__(256) void chunk_attn_kernel(
    const bf16* __restrict__ qf, const bf16* __restrict__ kf,
    const bf16* __restrict__ vf, const float* __restrict__ buf,
    float* __restrict__ out)
{
  int bh = blockIdx.x >> 5;
  int ck = blockIdx.x & 31;
  int b = bh >> 3, h = bh & 7;
  __shared__ short Qs[64 * 64];   // [t][m] natural swizzled
  __shared__ short Ks[64 * 64];   // [t][m]; reused as As[i][j] after phase 1
  __shared__ short VT[64 * 64];   // [d][t]
  __shared__ short S0T[64 * 64];  // [d][m]
  __shared__ float z0[64];
  __shared__ float dlds[64];
  __shared__ float dpartA[64];
  __shared__ float dpartQ[4][64];
  int tid = threadIdx.x;
  int lane = tid & 63, w = tid >> 6;
  int quad = lane >> 4, l16 = lane & 15;
  const size_t rb = ((size_t)(b * T_ + ck * 64)) * D_ + h * 64;

  // --- staging ---
  {
    int lr = lane >> 3;
    int fc = (lane & 7) ^ lr;
#pragma unroll
    for (int seg = 0; seg < 2; ++seg) {
      int r = 16 * w + 8 * seg;
      load16_lds((const short*)qf + rb + (size_t)(r + lr) * D_ + fc * 8, &Qs[r * 64]);
      load16_lds((const short*)kf + rb + (size_t)(r + lr) * D_ + fc * 8, &Ks[r * 64]);
    }
    int d = lane;
    const float* S0 = buf + (size_t)(bh * 31 + (ck > 0 ? ck - 1 : 0)) * CENT_;
#pragma unroll
    for (int cc0 = 0; cc0 < 2; ++cc0) {
      int cc = w + cc0 * 4;
      short8 vv, ss;
#pragma unroll
      for (int u = 0; u < 8; ++u) {
        vv[u] = ((const short*)vf)[rb + (size_t)(cc * 8 + u) * D_ + d];
        ss[u] = (ck > 0) ? (short)f2bf(S0[(size_t)(cc * 8 + u) * 64 + d]) : (short)0;
      }
      int slot = cc ^ (d & 7);
      *(short8*)&VT[d * 64 + slot * 8] = vv;
      *(short8*)&S0T[d * 64 + slot * 8] = ss;
    }
    if (tid < 64) z0[tid] = (ck > 0) ? S0[4096 + tid] : 0.f;
  }
  __syncthreads();

  // --- phase 1: A[i][j] = sum_m Qf[i][m] Kf[j][m] ---
  float4v pacc[4] = {};
  {
    int ar = 16 * w + l16;
    short8 afr[2];
#pragma unroll
    for (int s = 0; s < 2; ++s)
      afr[s] = *(const short8*)&Qs[ar * 64 + ((s * 4 + quad) ^ (ar & 7)) * 8];
#pragma unroll
    for (int nj = 0; nj < 4; ++nj) {
      int br = nj * 16 + l16;
#pragma unroll
      for (int s = 0; s < 2; ++s) {
        short8 bfr = *(const short8*)&Ks[br * 64 + ((s * 4 + quad) ^ (br & 7)) * 8];
        pacc[nj] = __builtin_amdgcn_mfma_f32_16x16x32_bf16(afr[s], bfr, pacc[nj], 0, 0, 0);
      }
    }
  }
  // den partial: qz[i] over m-chunks {w, w+4}
  {
    int i = lane;
    float qz = 0.f;
#pragma unroll
    for (int cc0 = 0; cc0 < 2; ++cc0) {
      int cc = w + cc0 * 4;
      short8 qq = *(const short8*)&Qs[i * 64 + (cc ^ (i & 7)) * 8];
#pragma unroll
      for (int u = 0; u < 8; ++u) qz += bf2f((unsigned short)qq[u]) * z0[cc * 8 + u];
    }
    dpartQ[w][i] = qz;
  }
  __syncthreads();               // all Ks frag reads done

  // --- mask + rowsum + write As (into Ks) ---
  {
    float rs[4] = {0.f, 0.f, 0.f, 0.f};
#pragma unroll
    for (int nj = 0; nj < 4; ++nj) {
#pragma unroll
      for (int r = 0; r < 4; ++r) {
        int i = 16 * w + quad * 4 + r;
        int j = nj * 16 + l16;
        float val = (j <= i) ? pacc[nj][r] : 0.f;
        rs[r] += val;
        ((unsigned short*)Ks)[i * 64 + ((j >> 3) ^ (i & 7)) * 8 + (j & 7)] = f2bf(val);
      }
    }
#pragma unroll
    for (int r = 0; r < 4; ++r) {
      float s = rs[r];
      s += __shfl_xor(s, 1, 64);
      s += __shfl_xor(s, 2, 64);
      s += __shfl_xor(s, 4, 64);
      s += __shfl_xor(s, 8, 64);
      rs[r] = s;
    }
    if (l16 == 0) {
#pragma unroll
      for (int r = 0; r < 4; ++r) dpartA[16 * w + quad * 4 + r] = rs[r];
    }
  }
  __syncthreads();
  if (tid < 64)
    dlds[tid] = dpartA[tid] + dpartQ[0][tid] + dpartQ[1][tid]
              + dpartQ[2][tid] + dpartQ[3][tid];

  // --- phase 2: num = As.V + Qf.S0 ---
  float4v acc[4] = {};
  {
    int ar = 16 * w + l16;
    short8 aA[2], aQ[2];
#pragma unroll
    for (int s = 0; s < 2; ++s) {
      aA[s] = *(const short8*)&Ks[ar * 64 + ((s * 4 + quad) ^ (ar & 7)) * 8];
      aQ[s] = *(const short8*)&Qs[ar * 64 + ((s * 4 + quad) ^ (ar & 7)) * 8];
    }
#pragma unroll
    for (int nd = 0; nd < 4; ++nd) {
      int br = nd * 16 + l16;
#pragma unroll
      for (int s = 0; s < 2; ++s) {
        short8 bV = *(const short8*)&VT[br * 64 + ((s * 4 + quad) ^ (br & 7)) * 8];
        acc[nd] = __builtin_amdgcn_mfma_f32_16x16x32_bf16(aA[s], bV, acc[nd], 0, 0, 0);
        short8 bS = *(const short8*)&S0T[br * 64 + ((s * 4 + quad) ^ (br & 7)) * 8];
        acc[nd] = __builtin_amdgcn_mfma_f32_16x16x32_bf16(aQ[s], bS, acc[nd], 0, 0, 0);
      }
    }
  }
  __syncthreads();               // dlds visible
#pragma unroll
  for (int nd = 0; nd < 4; ++nd)
#pragma unroll
    for (int r = 0; r < 4; ++r) {
      int i = 16 * w + quad * 4 + r;
      int d = nd * 16 + l16;
      out[((size_t)(b * T_ + ck * 64 + i)) * D_ + h * 64 + d] =
          acc[nd][r] / (dlds[i] + 1e-16f);
    }
}

// ---------------------------------------------------------------------------
// x[row,:] += LayerNorm(a[row,:]) * g + b ; also writes bf16 mirror xb
// ---------------------------------------------------------------------------
__global__ __launch_bounds__(256) void ln_add_kernel(
    float* __restrict__ x, bf16* __restrict__ xb, const float* __restrict__ a,
    const float* __restrict__ g, const float* __restrict__ bta)
{
  int row = blockIdx.x;
  int tid = threadIdx.x;
  const float* ar = a + (size_t)row * D_;
  float v0 = ar[tid], v1 = ar[tid + 256];
  __shared__ float red[4];
  float w = v0 + v1;
  for (int o = 32; o > 0; o >>= 1) w += __shfl_down(w, o, 64);
  if ((tid & 63) == 0) red[tid >> 6] = w;
  __syncthreads();
  float mu = (red[0] + red[1] + red[2] + red[3]) * (1.f / 512.f);
  float d0 = v0 - mu, d1 = v1 - mu;
  __syncthreads();
  w = d0 * d0 + d1 * d1;
  for (int o = 32; o > 0; o >>= 1) w += __shfl_down(w, o, 64);
  if ((tid & 63) == 0) red[tid >> 6] = w;
  __syncthreads();
  float var = (red[0] + red[1] + red[2] + red[3]) * (1.f / 512.f);
  float rs = rsqrtf(var + 1e-5f);
  size_t xoff = (size_t)row * D_;
  float n0 = x[xoff + tid]       + d0 * rs * g[tid]       + bta[tid];
  float n1 = x[xoff + tid + 256] + d1 * rs * g[tid + 256] + bta[tid + 256];
  x[xoff + tid]        = n0;
  x[xoff + tid + 256]  = n1;
  xb[xoff + tid]       = __float2bfloat16(n0);
  xb[xoff + tid + 256] = __float2bfloat16(n1);
}

// ---------------------------------------------------------------------------
extern "C" void kernel_launch(void* const* d_in, const int* in_sizes, int n_in,
                              void* d_out, int out_size, void* d_ws, size_t ws_size,
                              hipStream_t stream) {
  const int*   tokens = (const int*)  d_in[0];
  const float* emb    = (const float*)d_in[1];
  const float* Wq     = (const float*)d_in[2];
  const float* bq     = (const float*)d_in[3];
  const float* Wk     = (const float*)d_in[4];
  const float* bk     = (const float*)d_in[5];
  const float* Wv     = (const float*)d_in[6];
  const float* bv     = (const float*)d_in[7];
  const float* rfs    = (const float*)d_in[8];
  const float* ln1g   = (const float*)d_in[9];
  const float* ln1b   = (const float*)d_in[10];
  const float* ln2g   = (const float*)d_in[11];
  const float* ln2b   = (const float*)d_in[12];
  const float* WU     = (const float*)d_in[13];
  const float* bU     = (const float*)d_in[14];
  const float* WV     = (const float*)d_in[15];
  const float* bV     = (const float*)d_in[16];
  const float* Wout   = (const float*)d_in[17];
  const float* bout   = (const float*)d_in[18];
  float* out = (float*)d_out;

  const size_t R = (size_t)BT_ * D_;          // 2,097,152 floats (8 MB)
  float* ws = (float*)d_ws;
  float* x  = ws;                             // [0, R)
  float* ab = ws + R;                         // [R, 2R)
  float* sb = ws + 2 * R;                     // [2R, 3R) chunk states (7.9 MB)
  bf16*  qb = (bf16*)(ws + 3 * R);            // [3R, 3.5R) bf16 BT x D
  bf16*  kb = (bf16*)(ws + 3 * R + R / 2);    // [3.5R, 4R)
  bf16*  vb = (bf16*)(ws + 4 * R);            // [4R, 4.5R)
  bf16*  xb = (bf16*)(ws + 4 * R + R / 2);    // [4.5R, 5R)
  bf16*  hb = (bf16*)(ws + 5 * R);            // [5R, 7R) bf16 BT x FFN
  float* pb = ws + 7 * R;                     // [7R, 11R) split-K partials
  bf16*  wT = (bf16*)(ws + 11 * R);           // weights
  bf16* WqT   = wT;                            // [L][D][D] (RF-folded)
  bf16* WkT   = WqT + (size_t)2 * D_ * D_;
  bf16* WvT   = WkT + (size_t)2 * D_ * D_;
  bf16* WUT   = WvT + (size_t)2 * D_ * D_;     // [L][FFN][D]
  bf16* WVT   = WUT + (size_t)2 * D_ * FFN_;   // [L][D][FFN]
  bf16* WoutT = WVT + (size_t)2 * D_ * FFN_;   // [VOCAB][D]
  float* bqf  = (float*)(WoutT + (size_t)VOCAB_ * D_);
  float* bkf  = bqf + 2 * D_;

  // ---- weight prep ----
  rf_fold_w_kernel<<<dim3(8, 4, 4), 256, 0, stream>>>(Wq, Wk, rfs, WqT, WkT);
  prep_all_kernel<<<4740, 256, 0, stream>>>(
      Wv, WU, WV, Wout, WvT, WUT, WVT, WoutT, bq, bk, rfs, bqf, bkf);

  embed_pos_kernel<<<BT_, 512, 0, stream>>>(tokens, emb, x, xb);

  for (int l = 0; l < 2; ++l) {
    gemm_qkv<<<dim3(BT_/128, D_/128, 3), 256, 0, stream>>>(
        xb, wT, bqf, bkf, bv, qb, l);

    chunk_sum_kernel<<<16 * 31, 256, 0, stream>>>(kb, vb, sb);
    chunk_prefix_kernel<<<16 * 17, 256, 0, stream>>>(sb);
    chunk_attn_kernel<<<16 * NC_, 256, 0, stream>>>(qb, kb, vb, sb, ab);

    ln_add_kernel<<<BT_, 256, 0, stream>>>(x, xb, ab, ln1g + l*D_, ln1b + l*D_);

    gemm_mfma<<<dim3(BT_/128, FFN_/128), 256, 0, stream>>>(
        xb, WUT + (size_t)l*D_*FFN_, bU + l*FFN_, hb, BT_, FFN_, D_, 1);

    gemm_splitk<<<dim3(BT_/128, D_/128, 4), 256, 0, stream>>>(
        hb, WVT + (size_t)l*FFN_*D_, pb, BT_, D_, FFN_, FFN_/4);
    reduce_ln_add_kernel<<<BT_, 256, 0, stream>>>(
        pb, bV + l*D_, x, xb, ln2g + l*D_, ln2b + l*D_);
  }

  gemm_splitk<<<dim3(BT_/128, VOCAB_/128, 4), 256, 0, stream>>>(
      xb, WoutT, pb, BT_, VOCAB_, D_, D_/4);
  reduce4_bias_kernel<<<(BT_*VOCAB_)/1024, 256, 0, stream>>>(
      pb, bout, out, BT_*VOCAB_, VOCAB_);
}